// Round 11
// baseline (98.794 us; speedup 1.0000x reference)
//
#include <hip/hip_runtime.h>

#define P_TERMS 24

typedef _Float16 f16x8 __attribute__((ext_vector_type(8)));
typedef float f32x16 __attribute__((ext_vector_type(16)));

static __device__ __forceinline__ unsigned pk2(float a, float b) {
  unsigned d;
  asm("v_cvt_pkrtz_f16_f32 %0, %1, %2" : "=v"(d) : "v"(a), "v"(b));
  return d;
}
// d.lo = a.lo + b.hi ; d.hi = a.hi + b.lo   (f16x2, swapped src1)
static __device__ __forceinline__ unsigned pkadd_sw(unsigned a, unsigned b) {
  unsigned d;
  asm("v_pk_add_f16 %0, %1, %2 op_sel:[0,1] op_sel_hi:[1,0]"
      : "=v"(d) : "v"(a), "v"(b));
  return d;
}

// ---------------- K1: cp[p] = A^p B (sequential, tiny) -> Fp[p][n] --------
__global__ __launch_bounds__(256) void s4_powers(
    const float* __restrict__ A, const float* __restrict__ B,
    float* __restrict__ Fp) {
  __shared__ float cp[P_TERMS + 1][64];
  __shared__ float cur[64];
  const int tid = threadIdx.x;
  if (tid < 64) { cur[tid] = B[tid]; cp[0][tid] = B[tid]; }
  __syncthreads();
  const int n = tid >> 2, g = tid & 3;
  for (int p = 1; p <= P_TERMS; ++p) {
    float s = 0.f;
    const int j0 = g * 16;
#pragma unroll
    for (int j = 0; j < 16; ++j) s += A[n * 64 + j0 + j] * cur[j0 + j];
    s += __shfl_xor(s, 1);
    s += __shfl_xor(s, 2);
    __syncthreads();
    if (g == 0) { cur[n] = s; cp[p][n] = s; }
    __syncthreads();
  }
  for (int i = tid; i < (P_TERMS + 1) * 64; i += 256)
    Fp[i] = cp[i >> 6][i & 63];
}

// ------- K2h: H[n,k] = sum_p binom(k,p) dt^p cp[p][n]; store f16 [k/8][n][8]
__global__ __launch_bounds__(512) void s4_h8(
    const float* __restrict__ Fp, const float* __restrict__ log_dt,
    _Float16* __restrict__ H8) {
  __shared__ float Fm[P_TERMS + 1];
  const int n = blockIdx.x;
  const int k = threadIdx.x;  // 0..511
  if (k <= P_TERMS) Fm[k] = Fp[k * 64 + n];
  __syncthreads();
  const float dt = __expf(log_dt[0]);
  float coef = 1.f, s = Fm[0];
#pragma unroll 1
  for (int p = 1; p <= P_TERMS; ++p) {
    coef *= dt * (float)(k - p + 1) / (float)p;  // zero for p>k, stays zero
    s += coef * Fm[p];
  }
  H8[((size_t)(k >> 3) * 64 + n) * 8 + (k & 7)] = (_Float16)s;
}

// ------- K2c: Ct8[n/8][m][8] = C[m][n] (f16) ------------------------------
__global__ __launch_bounds__(256) void s4_ct(
    const float* __restrict__ C, _Float16* __restrict__ Ct8) {
  const int n = blockIdx.x;   // 0..63
  const int m = threadIdx.x;  // 0..255
  Ct8[((size_t)(n >> 3) * 256 + m) * 8 + (n & 7)] = (_Float16)C[m * 64 + n];
}

// ---------------- K3: rank-64 factored  Y = dt*(G@H^T)@C^T + 2 u D --------
// Stage 1: Z^T[n,t] = mfma(A=H, B=G). Z bounced via padded LDS that
// ALIASES the (dead after stage 1) UF8 buffer -> 36.9 KB LDS ->
// 4 blocks/CU, whole 1024-block grid resident; store phases of some
// blocks overlap compute phases of others.
__global__ __launch_bounds__(256, 4) void s4_main(
    const float* __restrict__ x, const _Float16* __restrict__ H8,
    const _Float16* __restrict__ Ct8, const float* __restrict__ Dvec,
    const float* __restrict__ log_dt, float* __restrict__ out) {
  __shared__ float us[512];  // u for this channel
  __shared__ union SBuf {
    uint4 UF8[1536];          // UF8[i] = f16{uf(i..i+7)}, uf(g)=u[g-512] guarded
    unsigned Zl[256][34];     // Z f16-pairs, padded rows (136B), after barrier
  } sh;

  const int tid = threadIdx.x;
  const int bid = blockIdx.x;
  const int th = bid & 1;  // t half
  const int ch = bid >> 1;
  const int b = ch >> 8;
  const int d = ch & 255;

  for (int i = tid; i < 512; i += 256) us[i] = x[(b * 512 + i) * 256 + d];
  __syncthreads();
  {
    const int i0 = tid * 6;  // 256*6 = 1536 windows
    float w[14];
#pragma unroll
    for (int j = 0; j < 14; ++j) {
      const int g = i0 + j - 512;
      const float v = us[g & 511];
      w[j] = (g >= 0 && g < 512) ? v : 0.f;
    }
    unsigned P[13];
#pragma unroll
    for (int j = 0; j < 13; ++j) P[j] = pk2(w[j], w[j + 1]);
#pragma unroll
    for (int e = 0; e < 6; ++e)
      sh.UF8[i0 + e] = make_uint4(P[e], P[e + 2], P[e + 4], P[e + 6]);
  }
  __syncthreads();

  const int lane = tid & 63;
  const int wid = tid >> 6;
  const int r = lane & 31;
  const int hi = lane >> 5;
  const int tw = wid * 64;        // local strip base (0..192)
  const int tg0 = th * 256 + tw;  // global strip base
  const int tl0 = tw + r;         // local t of tile0 row r

  // ---------------- stage 1: Z^T = H @ G ----------------
  f32x16 acc[2][2];  // [ti][ni]
#pragma unroll
  for (int ti = 0; ti < 2; ++ti)
#pragma unroll
    for (int ni = 0; ni < 2; ++ni)
#pragma unroll
      for (int e = 0; e < 16; ++e) acc[ti][ni][e] = 0.f;

  int ifj = 512 + tg0 + r + hi * 8;  // F(j) tile0; tile1 at +32
  int irj = 505 + tg0 + r - hi * 8;  // R(j) tile0; tile1 at +32
  const _Float16* hp = H8 + hi * 512 + r * 8;

#pragma unroll 1
  for (int j = 0; j < 32; ++j) {
    const uint4 F0 = sh.UF8[ifj];
    const uint4 R0 = sh.UF8[irj];
    const uint4 F1 = sh.UF8[ifj + 32];
    const uint4 R1 = sh.UF8[irj + 32];
    const f16x8 h0 = *reinterpret_cast<const f16x8*>(hp);
    const f16x8 h1 = *reinterpret_cast<const f16x8*>(hp + 256);
    union { unsigned w[4]; f16x8 v; } g0, g1;
    g0.w[0] = pkadd_sw(F0.x, R0.w);
    g0.w[1] = pkadd_sw(F0.y, R0.z);
    g0.w[2] = pkadd_sw(F0.z, R0.y);
    g0.w[3] = pkadd_sw(F0.w, R0.x);
    g1.w[0] = pkadd_sw(F1.x, R1.w);
    g1.w[1] = pkadd_sw(F1.y, R1.z);
    g1.w[2] = pkadd_sw(F1.z, R1.y);
    g1.w[3] = pkadd_sw(F1.w, R1.x);
    __builtin_amdgcn_s_setprio(1);
    acc[0][0] = __builtin_amdgcn_mfma_f32_32x32x16_f16(h0, g0.v, acc[0][0], 0, 0, 0);
    acc[0][1] = __builtin_amdgcn_mfma_f32_32x32x16_f16(h1, g0.v, acc[0][1], 0, 0, 0);
    acc[1][0] = __builtin_amdgcn_mfma_f32_32x32x16_f16(h0, g1.v, acc[1][0], 0, 0, 0);
    acc[1][1] = __builtin_amdgcn_mfma_f32_32x32x16_f16(h1, g1.v, acc[1][1], 0, 0, 0);
    __builtin_amdgcn_s_setprio(0);
    ifj += 16;
    irj -= 16;
    hp += 1024;
  }

  // all waves done reading UF8 before Zl overwrites it
  __syncthreads();

  // Z -> LDS (f16 pairs). D-layout: col t = lane&31, row n = (reg&3)+8q+4hi+32ni
#pragma unroll
  for (int ti = 0; ti < 2; ++ti) {
    const int t = tl0 + ti * 32;
#pragma unroll
    for (int ni = 0; ni < 2; ++ni) {
#pragma unroll
      for (int q = 0; q < 4; ++q) {
        uint2 v;
        v.x = pk2(acc[ti][ni][4 * q + 0], acc[ti][ni][4 * q + 1]);
        v.y = pk2(acc[ti][ni][4 * q + 2], acc[ti][ni][4 * q + 3]);
        *reinterpret_cast<uint2*>(&sh.Zl[t][ni * 16 + q * 4 + 2 * hi]) = v;
      }
    }
  }
  // wave reads only its own rows below; per-wave lgkm ordering suffices.

  // ---------------- stage 2: Y = Z @ C^T + 2uD ----------------
  const float dtv = __expf(log_dt[0]);
#pragma unroll 1
  for (int mp = 0; mp < 4; ++mp) {
    const int mb2 = mp * 64;
    f32x16 y[2][2];  // [ti][mi]
#pragma unroll
    for (int ti = 0; ti < 2; ++ti)
#pragma unroll
      for (int mi = 0; mi < 2; ++mi)
#pragma unroll
        for (int e = 0; e < 16; ++e) y[ti][mi][e] = 0.f;

#pragma unroll
    for (int ks = 0; ks < 4; ++ks) {
      const int c0 = 8 * ks + 4 * hi;
      union { uint2 u[2]; f16x8 v; } z0, z1;
      z0.u[0] = *reinterpret_cast<const uint2*>(&sh.Zl[tl0][c0]);
      z0.u[1] = *reinterpret_cast<const uint2*>(&sh.Zl[tl0][c0 + 2]);
      z1.u[0] = *reinterpret_cast<const uint2*>(&sh.Zl[tl0 + 32][c0]);
      z1.u[1] = *reinterpret_cast<const uint2*>(&sh.Zl[tl0 + 32][c0 + 2]);
      const _Float16* cb = Ct8 + ((size_t)(2 * ks + hi) * 256 + mb2 + r) * 8;
      const f16x8 c0f = *reinterpret_cast<const f16x8*>(cb);
      const f16x8 c1f = *reinterpret_cast<const f16x8*>(cb + 256);
      __builtin_amdgcn_s_setprio(1);
      y[0][0] = __builtin_amdgcn_mfma_f32_32x32x16_f16(z0.v, c0f, y[0][0], 0, 0, 0);
      y[0][1] = __builtin_amdgcn_mfma_f32_32x32x16_f16(z0.v, c1f, y[0][1], 0, 0, 0);
      y[1][0] = __builtin_amdgcn_mfma_f32_32x32x16_f16(z1.v, c0f, y[1][0], 0, 0, 0);
      y[1][1] = __builtin_amdgcn_mfma_f32_32x32x16_f16(z1.v, c1f, y[1][1], 0, 0, 0);
      __builtin_amdgcn_s_setprio(0);
    }

#pragma unroll
    for (int ti = 0; ti < 2; ++ti) {
      const int tb2 = th * 256 + tw + ti * 32 + 4 * hi;
#pragma unroll
      for (int mi = 0; mi < 2; ++mi) {
        const int m = mb2 + mi * 32 + r;
        const float Dm = Dvec[m];
#pragma unroll
        for (int reg = 0; reg < 16; ++reg) {
          const int trow = tb2 + (reg & 3) + 8 * (reg >> 2);
          const float uv = us[trow];
          out[(((size_t)b * 512 + trow) * 256 + d) * 256 + m] =
              dtv * y[ti][mi][reg] + 2.f * uv * Dm;
        }
      }
    }
  }
}

extern "C" void kernel_launch(void* const* d_in, const int* in_sizes, int n_in,
                              void* d_out, int out_size, void* d_ws, size_t ws_size,
                              hipStream_t stream) {
  (void)in_sizes; (void)n_in; (void)out_size; (void)ws_size;
  const float* x = (const float*)d_in[0];
  const float* A = (const float*)d_in[1];
  const float* B = (const float*)d_in[2];
  const float* C = (const float*)d_in[3];
  const float* D = (const float*)d_in[4];
  const float* log_dt = (const float*)d_in[5];
  float* out = (float*)d_out;

  float* Fp = (float*)d_ws;                          // 25*64*4   = 6.4 KB
  _Float16* H8 = (_Float16*)((char*)d_ws + 8192);    // 512*64*2  = 64 KB
  _Float16* Ct8 = (_Float16*)((char*)d_ws + 73728);  // 64*256*2  = 32 KB

  s4_powers<<<1, 256, 0, stream>>>(A, B, Fp);
  s4_h8<<<64, 512, 0, stream>>>(Fp, log_dt, H8);
  s4_ct<<<64, 256, 0, stream>>>(C, Ct8);
  s4_main<<<1024, 256, 0, stream>>>(x, H8, Ct8, D, log_dt, out);
}

// Round 12
// 85.132 us; speedup vs baseline: 1.1605x; 1.1605x over previous
//
#include <hip/hip_runtime.h>

#define P_TERMS 24

typedef _Float16 f16x8 __attribute__((ext_vector_type(8)));
typedef float f32x16 __attribute__((ext_vector_type(16)));

static __device__ __forceinline__ unsigned pk2(float a, float b) {
  unsigned d;
  asm("v_cvt_pkrtz_f16_f32 %0, %1, %2" : "=v"(d) : "v"(a), "v"(b));
  return d;
}
// d.lo = a.lo + b.hi ; d.hi = a.hi + b.lo   (f16x2, swapped src1)
static __device__ __forceinline__ unsigned pkadd_sw(unsigned a, unsigned b) {
  unsigned d;
  asm("v_pk_add_f16 %0, %1, %2 op_sel:[0,1] op_sel_hi:[1,0]"
      : "=v"(d) : "v"(a), "v"(b));
  return d;
}

// ---------------- K1: cp[p] = A^p B (sequential, tiny) -> Fp[p][n] --------
__global__ __launch_bounds__(256) void s4_powers(
    const float* __restrict__ A, const float* __restrict__ B,
    float* __restrict__ Fp) {
  __shared__ float cp[P_TERMS + 1][64];
  __shared__ float cur[64];
  const int tid = threadIdx.x;
  if (tid < 64) { cur[tid] = B[tid]; cp[0][tid] = B[tid]; }
  __syncthreads();
  const int n = tid >> 2, g = tid & 3;
  for (int p = 1; p <= P_TERMS; ++p) {
    float s = 0.f;
    const int j0 = g * 16;
#pragma unroll
    for (int j = 0; j < 16; ++j) s += A[n * 64 + j0 + j] * cur[j0 + j];
    s += __shfl_xor(s, 1);
    s += __shfl_xor(s, 2);
    __syncthreads();
    if (g == 0) { cur[n] = s; cp[p][n] = s; }
    __syncthreads();
  }
  for (int i = tid; i < (P_TERMS + 1) * 64; i += 256)
    Fp[i] = cp[i >> 6][i & 63];
}

// ------- K2h: H[n,k] = sum_p binom(k,p) dt^p cp[p][n]; store f16 [k/8][n][8]
__global__ __launch_bounds__(512) void s4_h8(
    const float* __restrict__ Fp, const float* __restrict__ log_dt,
    _Float16* __restrict__ H8) {
  __shared__ float Fm[P_TERMS + 1];
  const int n = blockIdx.x;
  const int k = threadIdx.x;  // 0..511
  if (k <= P_TERMS) Fm[k] = Fp[k * 64 + n];
  __syncthreads();
  const float dt = __expf(log_dt[0]);
  float coef = 1.f, s = Fm[0];
#pragma unroll 1
  for (int p = 1; p <= P_TERMS; ++p) {
    coef *= dt * (float)(k - p + 1) / (float)p;  // zero for p>k, stays zero
    s += coef * Fm[p];
  }
  H8[((size_t)(k >> 3) * 64 + n) * 8 + (k & 7)] = (_Float16)s;
}

// ------- K2c: Ct8[n/8][m][8] = C[m][n] (f16) ------------------------------
__global__ __launch_bounds__(256) void s4_ct(
    const float* __restrict__ C, _Float16* __restrict__ Ct8) {
  const int n = blockIdx.x;   // 0..63
  const int m = threadIdx.x;  // 0..255
  Ct8[((size_t)(n >> 3) * 256 + m) * 8 + (n & 7)] = (_Float16)C[m * 64 + n];
}

// ---------------- K3: rank-64 factored  Y = dt*(G@H^T)@C^T + 2 u D --------
// One block = one full channel (512 t). Per wave: stage1(th0) -> Zl ->
// INTERLEAVE{ stage1(th1) k-chunks  with  stage2(th0) store panels } ->
// Zl(th1) -> stage2(th1). Zl rows are wave-private: no barriers after
// build -> waves stay decorrelated AND stores overlap compute in-wave.
__global__ __launch_bounds__(256, 2) void s4_main(
    const float* __restrict__ x, const _Float16* __restrict__ H8,
    const _Float16* __restrict__ Ct8, const float* __restrict__ Dvec,
    const float* __restrict__ log_dt, float* __restrict__ out) {
  __shared__ float us[512];      // u for this channel
  __shared__ uint4 UF8[1536];    // UF8[i] = f16{uf(i..i+7)}, uf(g)=u[g-512] guarded
  __shared__ unsigned Zl[256][34];  // Z f16-pairs, padded rows (136B), wave-private

  const int tid = threadIdx.x;
  const int ch = blockIdx.x;
  const int b = ch >> 8;
  const int d = ch & 255;

  for (int i = tid; i < 512; i += 256) us[i] = x[(b * 512 + i) * 256 + d];
  __syncthreads();
  {
    const int i0 = tid * 6;  // 256*6 = 1536 windows
    float w[14];
#pragma unroll
    for (int j = 0; j < 14; ++j) {
      const int g = i0 + j - 512;
      const float v = us[g & 511];
      w[j] = (g >= 0 && g < 512) ? v : 0.f;
    }
    unsigned P[13];
#pragma unroll
    for (int j = 0; j < 13; ++j) P[j] = pk2(w[j], w[j + 1]);
#pragma unroll
    for (int e = 0; e < 6; ++e)
      UF8[i0 + e] = make_uint4(P[e], P[e + 2], P[e + 4], P[e + 6]);
  }
  __syncthreads();

  const int lane = tid & 63;
  const int wid = tid >> 6;
  const int r = lane & 31;
  const int hi = lane >> 5;
  const int tw = wid * 64;  // local strip base (0..192)
  const int tl0 = tw + r;   // local Zl row of tile0
  const float dtv = __expf(log_dt[0]);

  // ---- one k-step of stage 1 ----
  auto s1_step = [&](int& ifj, int& irj, const _Float16*& hp, f32x16 acc[2][2]) {
    const uint4 F0 = UF8[ifj];
    const uint4 R0 = UF8[irj];
    const uint4 F1 = UF8[ifj + 32];
    const uint4 R1 = UF8[irj + 32];
    const f16x8 h0 = *reinterpret_cast<const f16x8*>(hp);
    const f16x8 h1 = *reinterpret_cast<const f16x8*>(hp + 256);
    union { unsigned w[4]; f16x8 v; } g0, g1;
    g0.w[0] = pkadd_sw(F0.x, R0.w);
    g0.w[1] = pkadd_sw(F0.y, R0.z);
    g0.w[2] = pkadd_sw(F0.z, R0.y);
    g0.w[3] = pkadd_sw(F0.w, R0.x);
    g1.w[0] = pkadd_sw(F1.x, R1.w);
    g1.w[1] = pkadd_sw(F1.y, R1.z);
    g1.w[2] = pkadd_sw(F1.z, R1.y);
    g1.w[3] = pkadd_sw(F1.w, R1.x);
    __builtin_amdgcn_s_setprio(1);
    acc[0][0] = __builtin_amdgcn_mfma_f32_32x32x16_f16(h0, g0.v, acc[0][0], 0, 0, 0);
    acc[0][1] = __builtin_amdgcn_mfma_f32_32x32x16_f16(h1, g0.v, acc[0][1], 0, 0, 0);
    acc[1][0] = __builtin_amdgcn_mfma_f32_32x32x16_f16(h0, g1.v, acc[1][0], 0, 0, 0);
    acc[1][1] = __builtin_amdgcn_mfma_f32_32x32x16_f16(h1, g1.v, acc[1][1], 0, 0, 0);
    __builtin_amdgcn_s_setprio(0);
    ifj += 16;
    irj -= 16;
    hp += 1024;
  };

  // ---- Z -> LDS (wave-private rows) ----
  auto writeZ = [&](f32x16 acc[2][2]) {
#pragma unroll
    for (int ti = 0; ti < 2; ++ti) {
      const int t = tl0 + ti * 32;
#pragma unroll
      for (int ni = 0; ni < 2; ++ni) {
#pragma unroll
        for (int q = 0; q < 4; ++q) {
          uint2 v;
          v.x = pk2(acc[ti][ni][4 * q + 0], acc[ti][ni][4 * q + 1]);
          v.y = pk2(acc[ti][ni][4 * q + 2], acc[ti][ni][4 * q + 3]);
          *reinterpret_cast<uint2*>(&Zl[t][ni * 16 + q * 4 + 2 * hi]) = v;
        }
      }
    }
  };

  // ---- stage-2 panel: y = Z @ C^T for m-panel mp, then store ----
  auto s2_panel = [&](int mp, int th) {
    const int mb2 = mp * 64;
    f32x16 y[2][2];
#pragma unroll
    for (int ti = 0; ti < 2; ++ti)
#pragma unroll
      for (int mi = 0; mi < 2; ++mi)
#pragma unroll
        for (int e = 0; e < 16; ++e) y[ti][mi][e] = 0.f;
#pragma unroll
    for (int ks = 0; ks < 4; ++ks) {
      const int c0 = 8 * ks + 4 * hi;
      union { uint2 u[2]; f16x8 v; } z0, z1;
      z0.u[0] = *reinterpret_cast<const uint2*>(&Zl[tl0][c0]);
      z0.u[1] = *reinterpret_cast<const uint2*>(&Zl[tl0][c0 + 2]);
      z1.u[0] = *reinterpret_cast<const uint2*>(&Zl[tl0 + 32][c0]);
      z1.u[1] = *reinterpret_cast<const uint2*>(&Zl[tl0 + 32][c0 + 2]);
      const _Float16* cb = Ct8 + ((size_t)(2 * ks + hi) * 256 + mb2 + r) * 8;
      const f16x8 c0f = *reinterpret_cast<const f16x8*>(cb);
      const f16x8 c1f = *reinterpret_cast<const f16x8*>(cb + 256);
      __builtin_amdgcn_s_setprio(1);
      y[0][0] = __builtin_amdgcn_mfma_f32_32x32x16_f16(z0.v, c0f, y[0][0], 0, 0, 0);
      y[0][1] = __builtin_amdgcn_mfma_f32_32x32x16_f16(z0.v, c1f, y[0][1], 0, 0, 0);
      y[1][0] = __builtin_amdgcn_mfma_f32_32x32x16_f16(z1.v, c0f, y[1][0], 0, 0, 0);
      y[1][1] = __builtin_amdgcn_mfma_f32_32x32x16_f16(z1.v, c1f, y[1][1], 0, 0, 0);
      __builtin_amdgcn_s_setprio(0);
    }
#pragma unroll
    for (int ti = 0; ti < 2; ++ti) {
      const int tb2 = th * 256 + tw + ti * 32 + 4 * hi;
#pragma unroll
      for (int mi = 0; mi < 2; ++mi) {
        const int m = mb2 + mi * 32 + r;
        const float Dm = Dvec[m];
#pragma unroll
        for (int reg = 0; reg < 16; ++reg) {
          const int trow = tb2 + (reg & 3) + 8 * (reg >> 2);
          const float uv = us[trow];
          out[(((size_t)b * 512 + trow) * 256 + d) * 256 + m] =
              dtv * y[ti][mi][reg] + 2.f * uv * Dm;
        }
      }
    }
  };

  // ================= schedule =================
  f32x16 acc[2][2];
#pragma unroll
  for (int ti = 0; ti < 2; ++ti)
#pragma unroll
    for (int ni = 0; ni < 2; ++ni)
#pragma unroll
      for (int e = 0; e < 16; ++e) acc[ti][ni][e] = 0.f;

  // stage 1, th=0 (tg0 = tw)
  {
    int ifj = 512 + tw + r + hi * 8;
    int irj = 505 + tw + r - hi * 8;
    const _Float16* hp = H8 + hi * 512 + r * 8;
#pragma unroll 1
    for (int j = 0; j < 32; ++j) s1_step(ifj, irj, hp, acc);
  }
  writeZ(acc);

  // interleave: stage1 th=1 chunks with stage2 th=0 panels
  {
    int ifj = 512 + 256 + tw + r + hi * 8;
    int irj = 505 + 256 + tw + r - hi * 8;
    const _Float16* hp = H8 + hi * 512 + r * 8;
    f32x16 acc1[2][2];
#pragma unroll
    for (int ti = 0; ti < 2; ++ti)
#pragma unroll
      for (int ni = 0; ni < 2; ++ni)
#pragma unroll
        for (int e = 0; e < 16; ++e) acc1[ti][ni][e] = 0.f;

#pragma unroll 1
    for (int s = 0; s < 4; ++s) {
#pragma unroll 1
      for (int j2 = 0; j2 < 8; ++j2) s1_step(ifj, irj, hp, acc1);
      s2_panel(s, 0);
    }
    // wave-private rows: this wave finished reading its th0 Z above
    writeZ(acc1);
  }

  // stage 2, th=1 (store tail; overlaps other waves'/block's compute)
#pragma unroll 1
  for (int s = 0; s < 4; ++s) s2_panel(s, 1);
}

extern "C" void kernel_launch(void* const* d_in, const int* in_sizes, int n_in,
                              void* d_out, int out_size, void* d_ws, size_t ws_size,
                              hipStream_t stream) {
  (void)in_sizes; (void)n_in; (void)out_size; (void)ws_size;
  const float* x = (const float*)d_in[0];
  const float* A = (const float*)d_in[1];
  const float* B = (const float*)d_in[2];
  const float* C = (const float*)d_in[3];
  const float* D = (const float*)d_in[4];
  const float* log_dt = (const float*)d_in[5];
  float* out = (float*)d_out;

  float* Fp = (float*)d_ws;                          // 25*64*4   = 6.4 KB
  _Float16* H8 = (_Float16*)((char*)d_ws + 8192);    // 512*64*2  = 64 KB
  _Float16* Ct8 = (_Float16*)((char*)d_ws + 73728);  // 64*256*2  = 32 KB

  s4_powers<<<1, 256, 0, stream>>>(A, B, Fp);
  s4_h8<<<64, 512, 0, stream>>>(Fp, log_dt, H8);
  s4_ct<<<64, 256, 0, stream>>>(C, Ct8);
  s4_main<<<512, 256, 0, stream>>>(x, H8, Ct8, D, log_dt, out);
}